// Round 1
// baseline (473.933 us; speedup 1.0000x reference)
//
#include <hip/hip_runtime.h>

#define NROI 1000
#define NCLS 81
#define NB   8
#define NLANE (NB*NCLS)        // 648
#define MAXM 1024
#define MAXKEEP 200
#define SCORE_T 0.5f
#define IOU_T 0.5f

typedef unsigned long long u64;
typedef unsigned int u32;

// --- exact-order helpers (no FMA contraction; must match f32 numpy reference) ---

__device__ __forceinline__ void decode_box(const float* __restrict__ roi,
                                           const float* __restrict__ dl,
                                           float& oy1, float& ox1,
                                           float& oy2, float& ox2) {
#pragma clang fp contract(off)
  float y1 = roi[0], x1 = roi[1], y2 = roi[2], x2 = roi[3];
  float h = y2 - y1;
  float w = x2 - x1;
  float cy = y1 + 0.5f * h;
  float cx = x1 + 0.5f * w;
  float d0 = dl[0] * 0.1f;
  float d1 = dl[1] * 0.1f;
  float d2 = dl[2] * 0.2f;
  float d3 = dl[3] * 0.2f;
  float ncy = d0 * h + cy;
  float ncx = d1 * w + cx;
  float nh = expf(d2) * h;
  float nw = expf(d3) * w;
  oy1 = ncy - 0.5f * nh;
  ox1 = ncx - 0.5f * nw;
  oy2 = ncy + 0.5f * nh;
  ox2 = ncx + 0.5f * nw;
}

__device__ __forceinline__ float area_f(float y1, float x1, float y2, float x2) {
#pragma clang fp contract(off)
  return (y2 - y1) * (x2 - x1);
}

__device__ __forceinline__ float iou_f(float iy1, float ix1, float iy2, float ix2, float ia,
                                       float jy1, float jx1, float jy2, float jx2, float ja) {
#pragma clang fp contract(off)
  float yy1 = fmaxf(iy1, jy1);
  float xx1 = fmaxf(ix1, jx1);
  float yy2 = fminf(iy2, jy2);
  float xx2 = fminf(ix2, jx2);
  float ih = fmaxf(yy2 - yy1, 0.0f);
  float iw = fmaxf(xx2 - xx1, 0.0f);
  float inter = ih * iw;
  float den = ia + ja;
  den = den - inter;
  den = den + 1e-8f;
  return inter / den;
}

// --- kernel A: background rows (argmax over classes == 0) ---
__global__ void bg_kernel(const float* __restrict__ probs, int* __restrict__ bg) {
  int r = blockIdx.x * blockDim.x + threadIdx.x;
  if (r >= NB * NROI) return;
  const float* p = probs + (size_t)r * NCLS;
  float p0 = p[0];
  float m = -1.0f;
  for (int c = 1; c < NCLS; ++c) m = fmaxf(m, p[c]);
  bg[r] = (p0 >= m) ? 1 : 0;  // argmax==0 iff p0 >= every other (first-max rule)
}

// --- kernel B: per-(batch,class) lane: filter, sort, greedy NMS, compact ---
__global__ __launch_bounds__(256) void nms_kernel(
    const float* __restrict__ roi, const float* __restrict__ deltas,
    const float* __restrict__ probs, const int* __restrict__ bg,
    int* __restrict__ lane_count, float* __restrict__ lane_score,
    int* __restrict__ lane_n, int* __restrict__ lane_rank) {
  int lane = blockIdx.x;               // 0..647
  int b = lane / NCLS, c = lane % NCLS;
  int tid = threadIdx.x;

  __shared__ u64 skey[MAXM];
  __shared__ float sy1[MAXM], sx1[MAXM], sy2[MAXM], sx2[MAXM], sarea[MAXM];
  __shared__ int skeep[MAXM];
  __shared__ int scount;

  if (tid == 0) scount = 0;
  for (int i = tid; i < MAXM; i += 256) skey[i] = 0ull;
  __syncthreads();

  // candidates: score > 0.5 and not a background row.
  // (all candidates strictly dominate non-candidates, so the first M sorted
  //  positions == candidate positions in the reference's full argsort)
  for (int n = tid; n < NROI; n += 256) {
    int row = b * NROI + n;
    float s = probs[(size_t)row * NCLS + c];
    if (s > SCORE_T && bg[row] == 0) {
      int slot = atomicAdd(&scount, 1);
      // tie-break: equal scores -> smaller n first (stable argsort)
      skey[slot] = ((u64)__float_as_uint(s) << 32) | (u64)(0xFFFFFFFFu - (u32)n);
    }
  }
  __syncthreads();
  int M = scount;

  // bitonic sort descending over 1024 keys (zero-padded)
  for (int k = 2; k <= MAXM; k <<= 1) {
    for (int j = k >> 1; j > 0; j >>= 1) {
      __syncthreads();
      for (int i = tid; i < MAXM; i += 256) {
        int ixj = i ^ j;
        if (ixj > i) {
          u64 a = skey[i], bb = skey[ixj];
          bool swp = ((i & k) == 0) ? (a < bb) : (a > bb);
          if (swp) { skey[i] = bb; skey[ixj] = a; }
        }
      }
    }
  }
  __syncthreads();

  // decode candidate boxes into LDS (sorted order)
  for (int p = tid; p < M; p += 256) {
    u32 n = 0xFFFFFFFFu - (u32)(skey[p] & 0xFFFFFFFFull);
    int row = b * NROI + (int)n;
    float by1, bx1, by2, bx2;
    decode_box(roi + (size_t)row * 4, deltas + ((size_t)row * NCLS + c) * 4,
               by1, bx1, by2, bx2);
    sy1[p] = by1; sx1[p] = bx1; sy2[p] = by2; sx2[p] = bx2;
    sarea[p] = area_f(by1, bx1, by2, bx2);
    skeep[p] = 1;
  }
  __syncthreads();

  // greedy NMS: serial outer (sorted order), parallel suppression
  for (int i = 0; i < M - 1; ++i) {
    __syncthreads();
    if (!skeep[i]) continue;           // uniform branch
    float iy1 = sy1[i], ix1 = sx1[i], iy2 = sy2[i], ix2 = sx2[i], ia = sarea[i];
    for (int j = i + 1 + tid; j < M; j += 256) {
      if (!skeep[j]) continue;
      float v = iou_f(iy1, ix1, iy2, ix2, ia,
                      sy1[j], sx1[j], sy2[j], sx2[j], sarea[j]);
      if (v > IOU_T) skeep[j] = 0;
    }
  }
  __syncthreads();

  // compact first 200 kept (cumsum cap), preserving sorted order + rank
  if (tid == 0) {
    int cnt = 0;
    size_t base = (size_t)lane * MAXKEEP;
    for (int p = 0; p < M && cnt < MAXKEEP; ++p) {
      if (skeep[p]) {
        lane_score[base + cnt] = __uint_as_float((u32)(skey[p] >> 32));
        lane_n[base + cnt] = (int)(0xFFFFFFFFu - (u32)(skey[p] & 0xFFFFFFFFull));
        lane_rank[base + cnt] = p;   // position in full sorted order -> flat idx
        cnt++;
      }
    }
    lane_count[lane] = cnt;
  }
}

// --- kernel C: per-batch 81-way merge top-200 (one wave per batch) ---
__global__ __launch_bounds__(64) void merge_kernel(
    const float* __restrict__ roi, const float* __restrict__ deltas,
    const int* __restrict__ lane_count, const float* __restrict__ lane_score,
    const int* __restrict__ lane_n, const int* __restrict__ lane_rank,
    float* __restrict__ out_b, float* __restrict__ out_c, float* __restrict__ out_s) {
  int b = blockIdx.x;
  int t = threadIdx.x;
  int c0 = t, c1 = t + 64;
  int cnt0 = (c0 < NCLS) ? lane_count[b * NCLS + c0] : 0;
  int cnt1 = (c1 < NCLS) ? lane_count[b * NCLS + c1] : 0;
  int h0 = 0, h1 = 0;

  auto loadk = [&](int c, int h, int cnt) -> u64 {
    if (h >= cnt) return 0ull;
    size_t base = ((size_t)(b * NCLS + c)) * MAXKEEP + h;
    float s = lane_score[base];
    u32 flat = (u32)(c * NROI + lane_rank[base]);
    // tie-break: equal scores -> lower flat index first (lax.top_k rule)
    return ((u64)__float_as_uint(s) << 32) | (u64)(0xFFFFFFFFu - flat);
  };

  u64 k0 = (c0 < NCLS) ? loadk(c0, h0, cnt0) : 0ull;
  u64 k1 = (c1 < NCLS) ? loadk(c1, h1, cnt1) : 0ull;

  int out_t = 0;
  for (; out_t < MAXKEEP; ++out_t) {
    u64 k = k0 > k1 ? k0 : k1;
    for (int off = 32; off > 0; off >>= 1) {
      u64 o = (u64)__shfl_xor((unsigned long long)k, off);
      if (o > k) k = o;
    }
    if (k == 0ull) break;              // all lanes exhausted; rest are zeros
    if (k0 == k || k1 == k) {          // unique keys -> exactly one winner thread
      int c = (k0 == k) ? c0 : c1;
      int h = (k0 == k) ? h0 : h1;
      size_t base = ((size_t)(b * NCLS + c)) * MAXKEEP + h;
      int n = lane_n[base];
      int row = b * NROI + n;
      float by1, bx1, by2, bx2;
      decode_box(roi + (size_t)row * 4, deltas + ((size_t)row * NCLS + c) * 4,
                 by1, bx1, by2, bx2);
      by1 = fminf(fmaxf(by1, 0.0f), 1.0f);
      bx1 = fminf(fmaxf(bx1, 0.0f), 1.0f);
      by2 = fminf(fmaxf(by2, 0.0f), 1.0f);
      bx2 = fminf(fmaxf(bx2, 0.0f), 1.0f);
      size_t ob = ((size_t)b * MAXKEEP + out_t) * 4;
      out_b[ob + 0] = by1; out_b[ob + 1] = bx1;
      out_b[ob + 2] = by2; out_b[ob + 3] = bx2;
      out_c[b * MAXKEEP + out_t] = (float)c;
      out_s[b * MAXKEEP + out_t] = __uint_as_float((u32)(k >> 32));
      if (k0 == k) { h0 = h + 1; k0 = loadk(c0, h0, cnt0); }
      else         { h1 = h + 1; k1 = loadk(c1, h1, cnt1); }
    }
  }
  // zero-fill invalid tail (valid = score > 0)
  for (int tt = out_t + t; tt < MAXKEEP; tt += 64) {
    size_t ob = ((size_t)b * MAXKEEP + tt) * 4;
    out_b[ob + 0] = 0.0f; out_b[ob + 1] = 0.0f;
    out_b[ob + 2] = 0.0f; out_b[ob + 3] = 0.0f;
    out_c[b * MAXKEEP + tt] = 0.0f;
    out_s[b * MAXKEEP + tt] = 0.0f;
  }
}

extern "C" void kernel_launch(void* const* d_in, const int* in_sizes, int n_in,
                              void* d_out, int out_size, void* d_ws, size_t ws_size,
                              hipStream_t stream) {
  const float* roi    = (const float*)d_in[0];  // [8,1000,4]
  const float* deltas = (const float*)d_in[1];  // [8,1000,324]
  const float* probs  = (const float*)d_in[2];  // [8,1000,81]

  char* ws = (char*)d_ws;
  int*   bg         = (int*)(ws);                         // 32000 B
  int*   lane_count = (int*)(ws + 32768);                 // 2592 B
  float* lane_score = (float*)(ws + 36864);               // 518400 B
  int*   lane_n     = (int*)(ws + 36864 + 520192);        // 518400 B
  int*   lane_rank  = (int*)(ws + 36864 + 2 * 520192);    // 518400 B

  float* out_b = (float*)d_out;                 // [8,200,4]
  float* out_c = out_b + NB * MAXKEEP * 4;      // [8,200]
  float* out_s = out_c + NB * MAXKEEP;          // [8,200]

  bg_kernel<<<(NB * NROI + 255) / 256, 256, 0, stream>>>(probs, bg);
  nms_kernel<<<NLANE, 256, 0, stream>>>(roi, deltas, probs, bg,
                                        lane_count, lane_score, lane_n, lane_rank);
  merge_kernel<<<NB, 64, 0, stream>>>(roi, deltas, lane_count, lane_score,
                                      lane_n, lane_rank, out_b, out_c, out_s);
}

// Round 2
// 333.675 us; speedup vs baseline: 1.4203x; 1.4203x over previous
//
#include <hip/hip_runtime.h>

#define NROI 1000
#define NCLS 81
#define NB   8
#define NLANE (NB*NCLS)        // 648
#define MAXM 1024
#define MAXKEEP 200
#define SCORE_T 0.5f
#define IOU_T 0.5f
#define HBITS 13
#define HSIZE (1<<HBITS)       // 8192 buckets
#define SCAP 1024

typedef unsigned long long u64;
typedef unsigned int u32;

// --- exact-order helpers (no FMA contraction; must match f32 numpy reference) ---

__device__ __forceinline__ void decode_box(const float* __restrict__ roi,
                                           const float* __restrict__ dl,
                                           float& oy1, float& ox1,
                                           float& oy2, float& ox2) {
#pragma clang fp contract(off)
  float y1 = roi[0], x1 = roi[1], y2 = roi[2], x2 = roi[3];
  float h = y2 - y1;
  float w = x2 - x1;
  float cy = y1 + 0.5f * h;
  float cx = x1 + 0.5f * w;
  float d0 = dl[0] * 0.1f;
  float d1 = dl[1] * 0.1f;
  float d2 = dl[2] * 0.2f;
  float d3 = dl[3] * 0.2f;
  float ncy = d0 * h + cy;
  float ncx = d1 * w + cx;
  float nh = expf(d2) * h;
  float nw = expf(d3) * w;
  oy1 = ncy - 0.5f * nh;
  ox1 = ncx - 0.5f * nw;
  oy2 = ncy + 0.5f * nh;
  ox2 = ncx + 0.5f * nw;
}

__device__ __forceinline__ float area_f(float y1, float x1, float y2, float x2) {
#pragma clang fp contract(off)
  return (y2 - y1) * (x2 - x1);
}

__device__ __forceinline__ float iou_f(float iy1, float ix1, float iy2, float ix2, float ia,
                                       float jy1, float jx1, float jy2, float jx2, float ja) {
#pragma clang fp contract(off)
  float yy1 = fmaxf(iy1, jy1);
  float xx1 = fmaxf(ix1, jx1);
  float yy2 = fminf(iy2, jy2);
  float xx2 = fminf(ix2, jx2);
  float ih = fmaxf(yy2 - yy1, 0.0f);
  float iw = fmaxf(xx2 - xx1, 0.0f);
  float inter = ih * iw;
  float den = ia + ja;
  den = den - inter;
  den = den + 1e-8f;
  return inter / den;
}

// key packing: [63:32] score bits, [31:15] (131071-flat) so lower flat wins,
//              [14:5] n (payload only), [4:0] zero. Empty slot = 0.
__device__ __forceinline__ u64 pack_key(u32 sbits, int flat, int n) {
  return ((u64)sbits << 32) | ((u64)(131071 - flat) << 15) | ((u64)n << 5);
}

// --- kernel A: background rows (argmax over classes == 0), wave per row ---
__global__ __launch_bounds__(256) void bg_kernel(const float* __restrict__ probs,
                                                 int* __restrict__ bg) {
  int row = blockIdx.x * 4 + (threadIdx.x >> 6);
  int lane = threadIdx.x & 63;
  if (row >= NB * NROI) return;
  const float* p = probs + (size_t)row * NCLS;
  float m = -1e30f;
  for (int idx = 1 + lane; idx < NCLS; idx += 64) m = fmaxf(m, p[idx]);
  for (int off = 32; off; off >>= 1) m = fmaxf(m, __shfl_xor(m, off));
  if (lane == 0) bg[row] = (p[0] >= m) ? 1 : 0;  // argmax==0 iff p0 >= all others
}

// --- kernel B: per-(batch,class) lane: filter, sort, chunked greedy NMS, compact ---
__global__ __launch_bounds__(256) void nms_kernel(
    const float* __restrict__ roi, const float* __restrict__ deltas,
    const float* __restrict__ probs, const int* __restrict__ bg,
    int* __restrict__ lane_count, u64* __restrict__ lane_key) {
  int lane = blockIdx.x;               // 0..647
  int b = lane / NCLS, c = lane % NCLS;
  int tid = threadIdx.x;

  __shared__ u64 skey[MAXM];
  __shared__ float sy1[MAXM], sx1[MAXM], sy2[MAXM], sx2[MAXM], sarea[MAXM];
  __shared__ int skeep[MAXM];
  __shared__ u64 chunk_kept;
  __shared__ int scount;

  if (tid == 0) scount = 0;
  for (int i = tid; i < MAXM; i += 256) skey[i] = 0ull;
  __syncthreads();

  // candidates: score > 0.5 and not background. Candidates strictly dominate
  // all non-candidates, so candidate sorted positions == full-argsort positions.
  for (int n = tid; n < NROI; n += 256) {
    int row = b * NROI + n;
    float s = probs[(size_t)row * NCLS + c];
    if (s > SCORE_T && bg[row] == 0) {
      int slot = atomicAdd(&scount, 1);
      // tie-break: equal scores -> smaller n first (stable argsort)
      skey[slot] = ((u64)__float_as_uint(s) << 32) | (u64)(0xFFFFFFFFu - (u32)n);
    }
  }
  __syncthreads();
  int M = scount;

  // bitonic sort descending over 1024 keys (zero-padded)
  for (int k = 2; k <= MAXM; k <<= 1) {
    for (int j = k >> 1; j > 0; j >>= 1) {
      for (int i = tid; i < MAXM; i += 256) {
        int ixj = i ^ j;
        if (ixj > i) {
          u64 a = skey[i], bb = skey[ixj];
          bool swp = ((i & k) == 0) ? (a < bb) : (a > bb);
          if (swp) { skey[i] = bb; skey[ixj] = a; }
        }
      }
      __syncthreads();
    }
  }

  // decode candidate boxes into LDS (sorted order)
  for (int p = tid; p < M; p += 256) {
    u32 n = 0xFFFFFFFFu - (u32)(skey[p] & 0xFFFFFFFFull);
    int row = b * NROI + (int)n;
    float by1, bx1, by2, bx2;
    decode_box(roi + (size_t)row * 4, deltas + ((size_t)row * NCLS + c) * 4,
               by1, bx1, by2, bx2);
    sy1[p] = by1; sx1[p] = bx1; sy2[p] = by2; sx2[p] = bx2;
    sarea[p] = area_f(by1, bx1, by2, bx2);
    skeep[p] = 1;
  }

  // chunked greedy NMS: exact greedy semantics, 2 barriers per 64-candidate chunk
  int nchunks = (M + 63) >> 6;
  for (int ck = 0; ck < nchunks; ++ck) {
    int start = ck << 6;
    __syncthreads();    // skeep stable (prev cross-pass / decode)

    if (tid < 64) {     // wave 0: intra-chunk serial resolve, barrier-free
      int j = start + tid;
      bool alive = (j < M) && (skeep[j] != 0);
      float jy1 = sy1[j], jx1 = sx1[j], jy2 = sy2[j], jx2 = sx2[j], ja = sarea[j];
      u64 mask = 0;     // bit i: iou(box_{start+i}, box_j) > T, i < tid
      for (int i = 0; i < 63; ++i) {
        float iy1 = sy1[start + i], ix1 = sx1[start + i];
        float iy2 = sy2[start + i], ix2 = sx2[start + i], ia = sarea[start + i];
        if (alive && i < tid && (start + i) < M) {
          float v = iou_f(iy1, ix1, iy2, ix2, ia, jy1, jx1, jy2, jx2, ja);
          if (v > IOU_T) mask |= (1ull << i);
        }
      }
      u64 rem = ~__ballot(alive);          // initially-dead lanes marked removed
      for (int i = 0; i < 63; ++i) {       // uniform serial resolve
        if (!((rem >> i) & 1)) rem |= __ballot((mask >> i) & 1);
        else                   (void)__ballot(0);
      }
      bool kept = alive && !((rem >> tid) & 1);
      skeep[j] = kept ? 1 : 0;
      u64 km = __ballot(kept);
      if (tid == 0) chunk_kept = km;
    }
    __syncthreads();

    // cross-chunk: chunk's kept boxes suppress all later candidates (parallel)
    u64 km = chunk_kept;
    for (int j = start + 64 + tid; j < M; j += 256) {
      if (!skeep[j]) continue;
      float jy1 = sy1[j], jx1 = sx1[j], jy2 = sy2[j], jx2 = sx2[j], ja = sarea[j];
      u64 m2 = km;
      while (m2) {
        int i = __ffsll((unsigned long long)m2) - 1;
        m2 &= m2 - 1;
        int p = start + i;
        float v = iou_f(sy1[p], sx1[p], sy2[p], sx2[p], sarea[p],
                        jy1, jx1, jy2, jx2, ja);
        if (v > IOU_T) { skeep[j] = 0; break; }
      }
    }
  }
  __syncthreads();

  // compact first 200 kept (cumsum cap); emit packed keys (score, flat, n)
  if (tid == 0) {
    int cnt = 0;
    size_t base = (size_t)lane * MAXKEEP;
    for (int p = 0; p < M && cnt < MAXKEEP; ++p) {
      if (skeep[p]) {
        u32 sbits = (u32)(skey[p] >> 32);
        int n = (int)(0xFFFFFFFFu - (u32)(skey[p] & 0xFFFFFFFFull));
        lane_key[base + cnt] = pack_key(sbits, c * NROI + p, n);
        cnt++;
      }
    }
    lane_count[lane] = cnt;
  }
}

// --- kernel C: per-batch parallel top-200 (radix-select + bitonic), exact order ---
__global__ __launch_bounds__(256) void merge_kernel(
    const float* __restrict__ roi, const float* __restrict__ deltas,
    const int* __restrict__ lane_count, const u64* __restrict__ lane_key,
    float* __restrict__ out_b, float* __restrict__ out_c, float* __restrict__ out_s) {
  int b = blockIdx.x;
  int tid = threadIdx.x;

  __shared__ int hist[HSIZE];
  __shared__ int csum[256];
  __shared__ int cnts[NCLS];
  __shared__ int tb_sh, scnt_sh;
  __shared__ u64 surv[SCAP];

  for (int i = tid; i < HSIZE; i += 256) hist[i] = 0;
  for (int i = tid; i < NCLS; i += 256) cnts[i] = lane_count[b * NCLS + i];
  if (tid == 0) { tb_sh = 0; scnt_sh = 0; }
  __syncthreads();

  // histogram on top-13 mantissa bits (scores in (0.5,1): exponent constant,
  // so bucket order == score order)
  for (int s = tid; s < NCLS * MAXKEEP; s += 256) {
    int c = s / MAXKEEP, h = s % MAXKEEP;
    if (h < cnts[c]) {
      u64 k = lane_key[((size_t)(b * NCLS + c)) * MAXKEEP + h];
      u32 sb = (u32)(k >> 32);
      atomicAdd(&hist[(sb >> 10) & (HSIZE - 1)], 1);
    }
  }
  __syncthreads();

  // suffix sums; find tb = max bucket with sufsum >= 200 (0 if total < 200)
  int base = tid * 32;
  int psum = 0;
  for (int i = 0; i < 32; ++i) psum += hist[base + i];
  csum[tid] = psum;
  __syncthreads();
  if (tid == 0) {
    int acc = 0;
    for (int t = 255; t >= 0; --t) { acc += csum[t]; csum[t] = acc; }
  }
  __syncthreads();
  int acc = (tid < 255) ? csum[tid + 1] : 0;
  int local_tb = -1;
  for (int i = 31; i >= 0; --i) {
    acc += hist[base + i];
    if (acc >= MAXKEEP && local_tb < 0) local_tb = base + i;
  }
  if (local_tb >= 0) atomicMax(&tb_sh, local_tb);
  __syncthreads();
  int tb = tb_sh;

  // gather survivors (all keys in buckets >= tb; superset of exact top-200)
  for (int s = tid; s < NCLS * MAXKEEP; s += 256) {
    int c = s / MAXKEEP, h = s % MAXKEEP;
    if (h < cnts[c]) {
      u64 k = lane_key[((size_t)(b * NCLS + c)) * MAXKEEP + h];
      u32 sb = (u32)(k >> 32);
      if ((int)((sb >> 10) & (HSIZE - 1)) >= tb) {
        int pos = atomicAdd(&scnt_sh, 1);
        if (pos < SCAP) surv[pos] = k;
      }
    }
  }
  __syncthreads();
  int scnt = min(scnt_sh, SCAP);
  int size = 2;
  while (size < scnt) size <<= 1;
  for (int i = scnt + tid; i < size; i += 256) surv[i] = 0ull;
  __syncthreads();

  // bitonic sort descending by full key (score desc, flat asc)
  for (int k2 = 2; k2 <= size; k2 <<= 1) {
    for (int j = k2 >> 1; j > 0; j >>= 1) {
      for (int i = tid; i < size; i += 256) {
        int ixj = i ^ j;
        if (ixj > i) {
          u64 a = surv[i], bb = surv[ixj];
          bool swp = ((i & k2) == 0) ? (a < bb) : (a > bb);
          if (swp) { surv[i] = bb; surv[ixj] = a; }
        }
      }
      __syncthreads();
    }
  }

  // decode + write top-200 in parallel; zero-fill the rest
  for (int t = tid; t < MAXKEEP; t += 256) {
    size_t ob = ((size_t)b * MAXKEEP + t) * 4;
    if (t < scnt) {
      u64 k = surv[t];
      int flat = 131071 - (int)((k >> 15) & 0x1FFFF);
      int c = flat / NROI;
      int n = (int)((k >> 5) & 0x3FF);
      int row = b * NROI + n;
      float by1, bx1, by2, bx2;
      decode_box(roi + (size_t)row * 4, deltas + ((size_t)row * NCLS + c) * 4,
                 by1, bx1, by2, bx2);
      out_b[ob + 0] = fminf(fmaxf(by1, 0.0f), 1.0f);
      out_b[ob + 1] = fminf(fmaxf(bx1, 0.0f), 1.0f);
      out_b[ob + 2] = fminf(fmaxf(by2, 0.0f), 1.0f);
      out_b[ob + 3] = fminf(fmaxf(bx2, 0.0f), 1.0f);
      out_c[b * MAXKEEP + t] = (float)c;
      out_s[b * MAXKEEP + t] = __uint_as_float((u32)(k >> 32));
    } else {
      out_b[ob + 0] = 0.0f; out_b[ob + 1] = 0.0f;
      out_b[ob + 2] = 0.0f; out_b[ob + 3] = 0.0f;
      out_c[b * MAXKEEP + t] = 0.0f;
      out_s[b * MAXKEEP + t] = 0.0f;
    }
  }
}

extern "C" void kernel_launch(void* const* d_in, const int* in_sizes, int n_in,
                              void* d_out, int out_size, void* d_ws, size_t ws_size,
                              hipStream_t stream) {
  const float* roi    = (const float*)d_in[0];  // [8,1000,4]
  const float* deltas = (const float*)d_in[1];  // [8,1000,324]
  const float* probs  = (const float*)d_in[2];  // [8,1000,81]

  char* ws = (char*)d_ws;
  int* bg         = (int*)(ws);              // 32000 B
  int* lane_count = (int*)(ws + 32768);      // 2592 B
  u64* lane_key   = (u64*)(ws + 40960);      // 648*200*8 = 1,036,800 B

  float* out_b = (float*)d_out;                 // [8,200,4]
  float* out_c = out_b + NB * MAXKEEP * 4;      // [8,200]
  float* out_s = out_c + NB * MAXKEEP;          // [8,200]

  bg_kernel<<<(NB * NROI + 3) / 4, 256, 0, stream>>>(probs, bg);
  nms_kernel<<<NLANE, 256, 0, stream>>>(roi, deltas, probs, bg, lane_count, lane_key);
  merge_kernel<<<NB, 256, 0, stream>>>(roi, deltas, lane_count, lane_key,
                                       out_b, out_c, out_s);
}

// Round 3
// 319.588 us; speedup vs baseline: 1.4830x; 1.0441x over previous
//
#include <hip/hip_runtime.h>

#define NROI 1000
#define NCLS 81
#define NB   8
#define NLANE (NB*NCLS)        // 648
#define MAXM 1024
#define MAXKEEP 200
#define SCORE_T 0.5f
#define IOU_T 0.5f
#define HBITS 13
#define HSIZE (1<<HBITS)       // 8192 buckets
#define SCAP 1024

typedef unsigned long long u64;
typedef unsigned int u32;

// --- exact-order helpers (no FMA contraction; must match f32 numpy reference) ---

__device__ __forceinline__ void decode_box(const float* __restrict__ roi,
                                           const float* __restrict__ dl,
                                           float& oy1, float& ox1,
                                           float& oy2, float& ox2) {
#pragma clang fp contract(off)
  float y1 = roi[0], x1 = roi[1], y2 = roi[2], x2 = roi[3];
  float h = y2 - y1;
  float w = x2 - x1;
  float cy = y1 + 0.5f * h;
  float cx = x1 + 0.5f * w;
  float d0 = dl[0] * 0.1f;
  float d1 = dl[1] * 0.1f;
  float d2 = dl[2] * 0.2f;
  float d3 = dl[3] * 0.2f;
  float ncy = d0 * h + cy;
  float ncx = d1 * w + cx;
  float nh = expf(d2) * h;
  float nw = expf(d3) * w;
  oy1 = ncy - 0.5f * nh;
  ox1 = ncx - 0.5f * nw;
  oy2 = ncy + 0.5f * nh;
  ox2 = ncx + 0.5f * nw;
}

__device__ __forceinline__ float area_f(float y1, float x1, float y2, float x2) {
#pragma clang fp contract(off)
  return (y2 - y1) * (x2 - x1);
}

__device__ __forceinline__ float iou_f(float iy1, float ix1, float iy2, float ix2, float ia,
                                       float jy1, float jx1, float jy2, float jx2, float ja) {
#pragma clang fp contract(off)
  float yy1 = fmaxf(iy1, jy1);
  float xx1 = fmaxf(ix1, jx1);
  float yy2 = fminf(iy2, jy2);
  float xx2 = fminf(ix2, jx2);
  float ih = fmaxf(yy2 - yy1, 0.0f);
  float iw = fmaxf(xx2 - xx1, 0.0f);
  float inter = ih * iw;
  float den = ia + ja;
  den = den - inter;
  den = den + 1e-8f;
  return inter / den;
}

// key packing: [63:32] score bits, [31:15] (131071-flat) so lower flat wins,
//              [14:5] n (payload only), [4:0] zero. Empty slot = 0.
__device__ __forceinline__ u64 pack_key(u32 sbits, int flat, int n) {
  return ((u64)sbits << 32) | ((u64)(131071 - flat) << 15) | ((u64)n << 5);
}

// --- kernel 1: background rows (argmax over classes == 0), wave per row ---
__global__ __launch_bounds__(256) void bg_kernel(const float* __restrict__ probs,
                                                 int* __restrict__ bg) {
  int row = blockIdx.x * 4 + (threadIdx.x >> 6);
  int lane = threadIdx.x & 63;
  if (row >= NB * NROI) return;
  const float* p = probs + (size_t)row * NCLS;
  float m = -1e30f;
  for (int idx = 1 + lane; idx < NCLS; idx += 64) m = fmaxf(m, p[idx]);
  for (int off = 32; off; off >>= 1) m = fmaxf(m, __shfl_xor(m, off));
  if (lane == 0) bg[row] = (p[0] >= m) ? 1 : 0;  // argmax==0 iff p0 >= all others
}

// --- kernel 2: per-lane candidate gather + rank sort (2 barriers total) ---
__global__ __launch_bounds__(256) void gather_sort_kernel(
    const float* __restrict__ probs, const int* __restrict__ bg,
    int* __restrict__ cand_count, u64* __restrict__ sorted_key) {
  int lane = blockIdx.x;               // 0..647
  int b = lane / NCLS, c = lane % NCLS;
  int tid = threadIdx.x;

  __shared__ u64 skey[MAXM];
  __shared__ int scount;
  if (tid == 0) scount = 0;
  __syncthreads();

  // candidates: score > 0.5 and not background. Candidates strictly dominate
  // non-candidates, so candidate sorted positions == full-argsort positions.
  for (int n = tid; n < NROI; n += 256) {
    int row = b * NROI + n;
    float s = probs[(size_t)row * NCLS + c];
    if (s > SCORE_T && bg[row] == 0) {
      int slot = atomicAdd(&scount, 1);
      if (slot < MAXM)
        skey[slot] = ((u64)__float_as_uint(s) << 32) | (u64)(0xFFFFFFFFu - (u32)n);
    }
  }
  __syncthreads();
  int M = min(scount, MAXM);

  // rank sort: keys unique -> rank = #{q: key_q > key_p} is a permutation.
  u64 myk[4]; int myr[4];
  for (int r = 0; r < 4; ++r) {
    int p = tid + (r << 8);
    myk[r] = (p < M) ? skey[p] : 0ull;
    myr[r] = 0;
  }
  for (int q = 0; q < M; ++q) {        // broadcast LDS read, conflict-free
    u64 kq = skey[q];
    if (kq > myk[0]) myr[0]++;
    if (kq > myk[1]) myr[1]++;
    if (kq > myk[2]) myr[2]++;
    if (kq > myk[3]) myr[3]++;
  }
  for (int r = 0; r < 4; ++r) {
    int p = tid + (r << 8);
    if (p < M) sorted_key[((size_t)lane << 10) + myr[r]] = myk[r];
  }
  if (tid == 0) cand_count[lane] = M;
}

// --- kernel 3: per-lane decode + chunked greedy NMS + parallel compact ---
__global__ __launch_bounds__(256) void nms_kernel(
    const float* __restrict__ roi, const float* __restrict__ deltas,
    const int* __restrict__ cand_count, const u64* __restrict__ sorted_key,
    int* __restrict__ keep_count, u64* __restrict__ lane_key) {
  int lane = blockIdx.x;
  int b = lane / NCLS, c = lane % NCLS;
  int tid = threadIdx.x;

  __shared__ float sy1[MAXM], sx1[MAXM], sy2[MAXM], sx2[MAXM], sarea[MAXM];
  __shared__ int skeep[MAXM];
  __shared__ u64 chunk_kept;
  __shared__ int segcnt[16], segbase[16];

  int M = cand_count[lane];
  for (int p = tid; p < MAXM; p += 256) skeep[p] = 0;

  // decode sorted candidates into LDS (coalesced key load)
  for (int p = tid; p < M; p += 256) {
    u64 k = sorted_key[((size_t)lane << 10) + p];
    u32 n = 0xFFFFFFFFu - (u32)(k & 0xFFFFFFFFull);
    int row = b * NROI + (int)n;
    float by1, bx1, by2, bx2;
    decode_box(roi + (size_t)row * 4, deltas + ((size_t)row * NCLS + c) * 4,
               by1, bx1, by2, bx2);
    sy1[p] = by1; sx1[p] = bx1; sy2[p] = by2; sx2[p] = bx2;
    sarea[p] = area_f(by1, bx1, by2, bx2);
    skeep[p] = 1;
  }

  // chunked greedy NMS: exact greedy semantics, 2 barriers per 64-candidate chunk
  int nchunks = (M + 63) >> 6;
  for (int ck = 0; ck < nchunks; ++ck) {
    int start = ck << 6;
    __syncthreads();

    if (tid < 64) {     // wave 0: intra-chunk serial resolve, barrier-free
      int j = start + tid;
      bool alive = (j < M) && (skeep[j] != 0);
      float jy1 = sy1[j], jx1 = sx1[j], jy2 = sy2[j], jx2 = sx2[j], ja = sarea[j];
      u64 mask = 0;     // bit i: iou(box_{start+i}, box_j) > T, i < tid
      for (int i = 0; i < 63; ++i) {
        float iy1 = sy1[start + i], ix1 = sx1[start + i];
        float iy2 = sy2[start + i], ix2 = sx2[start + i], ia = sarea[start + i];
        if (alive && i < tid && (start + i) < M) {
          float v = iou_f(iy1, ix1, iy2, ix2, ia, jy1, jx1, jy2, jx2, ja);
          if (v > IOU_T) mask |= (1ull << i);
        }
      }
      u64 rem = ~__ballot(alive);          // initially-dead lanes marked removed
      for (int i = 0; i < 63; ++i) {       // uniform serial resolve
        if (!((rem >> i) & 1)) rem |= __ballot((mask >> i) & 1);
        else                   (void)__ballot(0);
      }
      bool kept = alive && !((rem >> tid) & 1);
      skeep[j] = kept ? 1 : 0;
      u64 km = __ballot(kept);
      if (tid == 0) chunk_kept = km;
    }
    __syncthreads();

    // cross-chunk: chunk's kept boxes suppress all later candidates (parallel)
    u64 km = chunk_kept;
    for (int j = start + 64 + tid; j < M; j += 256) {
      if (!skeep[j]) continue;
      float jy1 = sy1[j], jx1 = sx1[j], jy2 = sy2[j], jx2 = sx2[j], ja = sarea[j];
      u64 m2 = km;
      while (m2) {
        int i = __ffsll((unsigned long long)m2) - 1;
        m2 &= m2 - 1;
        int p = start + i;
        float v = iou_f(sy1[p], sx1[p], sy2[p], sx2[p], sarea[p],
                        jy1, jx1, jy2, jx2, ja);
        if (v > IOU_T) { skeep[j] = 0; break; }
      }
    }
  }
  __syncthreads();

  // parallel compaction: first min(total,200) kept, in sorted order
  int w = tid >> 6, l = tid & 63;
  u64 segmask[4];
  for (int s = 0; s < 4; ++s) {
    int seg = (w << 2) + s;
    bool kept = skeep[(seg << 6) + l] != 0;
    u64 bal = __ballot(kept);
    segmask[s] = bal;
    if (l == 0) segcnt[seg] = __popcll(bal);
  }
  __syncthreads();
  if (tid < 16) {
    int acc = 0;
    for (int i = 0; i < tid; ++i) acc += segcnt[i];
    segbase[tid] = acc;
  }
  __syncthreads();
  int total = segbase[15] + segcnt[15];
  for (int s = 0; s < 4; ++s) {
    int seg = (w << 2) + s;
    int p = (seg << 6) + l;
    if (skeep[p] != 0) {
      int rank = segbase[seg] + __popcll(segmask[s] & ((1ull << l) - 1ull));
      if (rank < MAXKEEP) {
        u64 k = sorted_key[((size_t)lane << 10) + p];
        u32 sbits = (u32)(k >> 32);
        int n = (int)(0xFFFFFFFFu - (u32)(k & 0xFFFFFFFFull));
        lane_key[(size_t)lane * MAXKEEP + rank] = pack_key(sbits, c * NROI + p, n);
      }
    }
  }
  if (tid == 0) keep_count[lane] = min(total, MAXKEEP);
}

// --- kernel 4: per-batch parallel top-200 (radix-select + bitonic), exact order ---
__global__ __launch_bounds__(256) void merge_kernel(
    const float* __restrict__ roi, const float* __restrict__ deltas,
    const int* __restrict__ keep_count, const u64* __restrict__ lane_key,
    float* __restrict__ out_b, float* __restrict__ out_c, float* __restrict__ out_s) {
  int b = blockIdx.x;
  int tid = threadIdx.x;

  __shared__ int hist[HSIZE];
  __shared__ int csum[256];
  __shared__ int cnts[NCLS];
  __shared__ int tb_sh, scnt_sh;
  __shared__ u64 surv[SCAP];

  for (int i = tid; i < HSIZE; i += 256) hist[i] = 0;
  for (int i = tid; i < NCLS; i += 256) cnts[i] = keep_count[b * NCLS + i];
  if (tid == 0) { tb_sh = 0; scnt_sh = 0; }
  __syncthreads();

  // histogram on top-13 mantissa bits (scores in (0.5,1): exponent constant,
  // so bucket order == score order)
  for (int s = tid; s < NCLS * MAXKEEP; s += 256) {
    int c = s / MAXKEEP, h = s % MAXKEEP;
    if (h < cnts[c]) {
      u64 k = lane_key[((size_t)(b * NCLS + c)) * MAXKEEP + h];
      u32 sb = (u32)(k >> 32);
      atomicAdd(&hist[(sb >> 10) & (HSIZE - 1)], 1);
    }
  }
  __syncthreads();

  // suffix sums; find tb = max bucket with sufsum >= 200 (0 if total < 200)
  int base = tid * 32;
  int psum = 0;
  for (int i = 0; i < 32; ++i) psum += hist[base + i];
  csum[tid] = psum;
  __syncthreads();
  if (tid == 0) {
    int acc = 0;
    for (int t = 255; t >= 0; --t) { acc += csum[t]; csum[t] = acc; }
  }
  __syncthreads();
  int acc = (tid < 255) ? csum[tid + 1] : 0;
  int local_tb = -1;
  for (int i = 31; i >= 0; --i) {
    acc += hist[base + i];
    if (acc >= MAXKEEP && local_tb < 0) local_tb = base + i;
  }
  if (local_tb >= 0) atomicMax(&tb_sh, local_tb);
  __syncthreads();
  int tb = tb_sh;

  // gather survivors (all keys in buckets >= tb; superset of exact top-200)
  for (int s = tid; s < NCLS * MAXKEEP; s += 256) {
    int c = s / MAXKEEP, h = s % MAXKEEP;
    if (h < cnts[c]) {
      u64 k = lane_key[((size_t)(b * NCLS + c)) * MAXKEEP + h];
      u32 sb = (u32)(k >> 32);
      if ((int)((sb >> 10) & (HSIZE - 1)) >= tb) {
        int pos = atomicAdd(&scnt_sh, 1);
        if (pos < SCAP) surv[pos] = k;
      }
    }
  }
  __syncthreads();
  int scnt = min(scnt_sh, SCAP);
  int size = 2;
  while (size < scnt) size <<= 1;
  for (int i = scnt + tid; i < size; i += 256) surv[i] = 0ull;
  __syncthreads();

  // bitonic sort descending by full key (score desc, flat asc)
  for (int k2 = 2; k2 <= size; k2 <<= 1) {
    for (int j = k2 >> 1; j > 0; j >>= 1) {
      for (int i = tid; i < size; i += 256) {
        int ixj = i ^ j;
        if (ixj > i) {
          u64 a = surv[i], bb = surv[ixj];
          bool swp = ((i & k2) == 0) ? (a < bb) : (a > bb);
          if (swp) { surv[i] = bb; surv[ixj] = a; }
        }
      }
      __syncthreads();
    }
  }

  // decode + write top-200 in parallel; zero-fill the rest
  for (int t = tid; t < MAXKEEP; t += 256) {
    size_t ob = ((size_t)b * MAXKEEP + t) * 4;
    if (t < scnt) {
      u64 k = surv[t];
      int flat = 131071 - (int)((k >> 15) & 0x1FFFF);
      int c = flat / NROI;
      int n = (int)((k >> 5) & 0x3FF);
      int row = b * NROI + n;
      float by1, bx1, by2, bx2;
      decode_box(roi + (size_t)row * 4, deltas + ((size_t)row * NCLS + c) * 4,
                 by1, bx1, by2, bx2);
      out_b[ob + 0] = fminf(fmaxf(by1, 0.0f), 1.0f);
      out_b[ob + 1] = fminf(fmaxf(bx1, 0.0f), 1.0f);
      out_b[ob + 2] = fminf(fmaxf(by2, 0.0f), 1.0f);
      out_b[ob + 3] = fminf(fmaxf(bx2, 0.0f), 1.0f);
      out_c[b * MAXKEEP + t] = (float)c;
      out_s[b * MAXKEEP + t] = __uint_as_float((u32)(k >> 32));
    } else {
      out_b[ob + 0] = 0.0f; out_b[ob + 1] = 0.0f;
      out_b[ob + 2] = 0.0f; out_b[ob + 3] = 0.0f;
      out_c[b * MAXKEEP + t] = 0.0f;
      out_s[b * MAXKEEP + t] = 0.0f;
    }
  }
}

extern "C" void kernel_launch(void* const* d_in, const int* in_sizes, int n_in,
                              void* d_out, int out_size, void* d_ws, size_t ws_size,
                              hipStream_t stream) {
  const float* roi    = (const float*)d_in[0];  // [8,1000,4]
  const float* deltas = (const float*)d_in[1];  // [8,1000,324]
  const float* probs  = (const float*)d_in[2];  // [8,1000,81]

  char* ws = (char*)d_ws;
  int* bg         = (int*)(ws);                   // 32000 B
  int* cand_count = (int*)(ws + 32768);           // 2592 B
  int* keep_count = (int*)(ws + 36864);           // 2592 B
  u64* lane_key   = (u64*)(ws + 40960);           // 648*200*8 = 1,036,800 B
  u64* sorted_key = (u64*)(ws + 40960 + 1081344); // 648*1024*8 = 5,308,416 B

  float* out_b = (float*)d_out;                 // [8,200,4]
  float* out_c = out_b + NB * MAXKEEP * 4;      // [8,200]
  float* out_s = out_c + NB * MAXKEEP;          // [8,200]

  bg_kernel<<<(NB * NROI + 3) / 4, 256, 0, stream>>>(probs, bg);
  gather_sort_kernel<<<NLANE, 256, 0, stream>>>(probs, bg, cand_count, sorted_key);
  nms_kernel<<<NLANE, 256, 0, stream>>>(roi, deltas, cand_count, sorted_key,
                                        keep_count, lane_key);
  merge_kernel<<<NB, 256, 0, stream>>>(roi, deltas, keep_count, lane_key,
                                       out_b, out_c, out_s);
}

// Round 4
// 259.331 us; speedup vs baseline: 1.8275x; 1.2324x over previous
//
#include <hip/hip_runtime.h>

#define NROI 1000
#define NCLS 81
#define NB   8
#define NLANE (NB*NCLS)        // 648
#define MAXM 1024
#define MAXKEEP 200
#define SCORE_T 0.5f
#define IOU_T 0.5f
#define HBITS 13
#define HSIZE (1<<HBITS)       // 8192 buckets
#define SCAP 1024

typedef unsigned long long u64;
typedef unsigned int u32;

// --- exact-order helpers (no FMA contraction; must match f32 numpy reference) ---

__device__ __forceinline__ void decode_box(const float* __restrict__ roi,
                                           const float* __restrict__ dl,
                                           float& oy1, float& ox1,
                                           float& oy2, float& ox2) {
#pragma clang fp contract(off)
  float y1 = roi[0], x1 = roi[1], y2 = roi[2], x2 = roi[3];
  float h = y2 - y1;
  float w = x2 - x1;
  float cy = y1 + 0.5f * h;
  float cx = x1 + 0.5f * w;
  float d0 = dl[0] * 0.1f;
  float d1 = dl[1] * 0.1f;
  float d2 = dl[2] * 0.2f;
  float d3 = dl[3] * 0.2f;
  float ncy = d0 * h + cy;
  float ncx = d1 * w + cx;
  float nh = expf(d2) * h;
  float nw = expf(d3) * w;
  oy1 = ncy - 0.5f * nh;
  ox1 = ncx - 0.5f * nw;
  oy2 = ncy + 0.5f * nh;
  ox2 = ncx + 0.5f * nw;
}

__device__ __forceinline__ float area_f(float y1, float x1, float y2, float x2) {
#pragma clang fp contract(off)
  return (y2 - y1) * (x2 - x1);
}

__device__ __forceinline__ float iou_f(float iy1, float ix1, float iy2, float ix2, float ia,
                                       float jy1, float jx1, float jy2, float jx2, float ja) {
#pragma clang fp contract(off)
  float yy1 = fmaxf(iy1, jy1);
  float xx1 = fmaxf(ix1, jx1);
  float yy2 = fminf(iy2, jy2);
  float xx2 = fminf(ix2, jx2);
  float ih = fmaxf(yy2 - yy1, 0.0f);
  float iw = fmaxf(xx2 - xx1, 0.0f);
  float inter = ih * iw;
  float den = ia + ja;
  den = den - inter;
  den = den + 1e-8f;
  return inter / den;
}

// key packing: [63:32] score bits, [31:15] (131071-flat) so lower flat wins,
//              [14:5] n (payload only), [4:0] zero. Empty slot = 0.
__device__ __forceinline__ u64 pack_key(u32 sbits, int flat, int n) {
  return ((u64)sbits << 32) | ((u64)(131071 - flat) << 15) | ((u64)n << 5);
}

// --- kernel 1: background rows (argmax over classes == 0), wave per row ---
__global__ __launch_bounds__(256) void bg_kernel(const float* __restrict__ probs,
                                                 int* __restrict__ bg) {
  int row = blockIdx.x * 4 + (threadIdx.x >> 6);
  int lane = threadIdx.x & 63;
  if (row >= NB * NROI) return;
  const float* p = probs + (size_t)row * NCLS;
  float m = -1e30f;
  for (int idx = 1 + lane; idx < NCLS; idx += 64) m = fmaxf(m, p[idx]);
  for (int off = 32; off; off >>= 1) m = fmaxf(m, __shfl_xor(m, off));
  if (lane == 0) bg[row] = (p[0] >= m) ? 1 : 0;  // argmax==0 iff p0 >= all others
}

// --- kernel 2: per-lane candidate gather + rank sort ---
__global__ __launch_bounds__(256) void gather_sort_kernel(
    const float* __restrict__ probs, const int* __restrict__ bg,
    int* __restrict__ cand_count, u64* __restrict__ sorted_key) {
  int lane = blockIdx.x;               // 0..647
  int b = lane / NCLS, c = lane % NCLS;
  int tid = threadIdx.x;
  int wl = tid & 63;

  __shared__ u64 skey[MAXM];
  __shared__ int scount;
  if (tid == 0) scount = 0;
  __syncthreads();

  // candidates: score > 0.5 and not background. Candidates strictly dominate
  // non-candidates, so candidate sorted positions == full-argsort positions.
  // wave-aggregated ballot append (4 atomics per pass instead of ~500)
  for (int base_n = 0; base_n < NROI; base_n += 256) {
    int n = base_n + tid;
    bool cand = false;
    float s = 0.0f;
    if (n < NROI) {
      int row = b * NROI + n;
      s = probs[(size_t)row * NCLS + c];
      cand = (s > SCORE_T) && (bg[row] == 0);
    }
    u64 bal = __ballot(cand);
    int wbase = 0;
    if (wl == 0) wbase = atomicAdd(&scount, __popcll(bal));
    wbase = __shfl(wbase, 0);
    if (cand) {
      int off = __popcll(bal & ((1ull << wl) - 1ull));
      skey[wbase + off] = ((u64)__float_as_uint(s) << 32) | (u64)(0xFFFFFFFFu - (u32)n);
    }
  }
  __syncthreads();
  int M = min(scount, MAXM);

  // rank sort: keys unique -> rank = #{q: key_q > key_p} is a permutation.
  u64 myk[4]; int myr[4];
  for (int r = 0; r < 4; ++r) {
    int p = tid + (r << 8);
    myk[r] = (p < M) ? skey[p] : 0ull;
    myr[r] = 0;
  }
  for (int q = 0; q < M; ++q) {        // broadcast LDS read, conflict-free
    u64 kq = skey[q];
    if (kq > myk[0]) myr[0]++;
    if (kq > myk[1]) myr[1]++;
    if (kq > myk[2]) myr[2]++;
    if (kq > myk[3]) myr[3]++;
  }
  for (int r = 0; r < 4; ++r) {
    int p = tid + (r << 8);
    if (p < M) sorted_key[((size_t)lane << 10) + myr[r]] = myk[r];
  }
  if (tid == 0) cand_count[lane] = M;
}

// --- kernel 3: per-lane decode + bulk-mask chunked greedy NMS + parallel compact ---
__global__ __launch_bounds__(256) void nms_kernel(
    const float* __restrict__ roi, const float* __restrict__ deltas,
    const int* __restrict__ cand_count, const u64* __restrict__ sorted_key,
    int* __restrict__ keep_count, u64* __restrict__ lane_key) {
  int lane = blockIdx.x;
  int b = lane / NCLS, c = lane % NCLS;
  int tid = threadIdx.x;

  __shared__ float4 sbox[MAXM];        // 16 KB
  __shared__ float sarea[MAXM];        // 4 KB
  __shared__ u64 hmask[MAXM];          // 8 KB: this chunk's 64-bit hit masks
  __shared__ int skeep[MAXM];          // 4 KB
  __shared__ u64 chunk_kept;
  __shared__ int segcnt[16], segbase[16];

  int M = cand_count[lane];
  for (int p = tid; p < MAXM; p += 256) skeep[p] = 0;

  // decode sorted candidates into LDS (float4-packed)
  for (int p = tid; p < M; p += 256) {
    u64 k = sorted_key[((size_t)lane << 10) + p];
    u32 n = 0xFFFFFFFFu - (u32)(k & 0xFFFFFFFFull);
    int row = b * NROI + (int)n;
    float by1, bx1, by2, bx2;
    decode_box(roi + (size_t)row * 4, deltas + ((size_t)row * NCLS + c) * 4,
               by1, bx1, by2, bx2);
    sbox[p] = make_float4(by1, bx1, by2, bx2);
    sarea[p] = area_f(by1, bx1, by2, bx2);
    skeep[p] = 1;
  }

  // chunked greedy NMS, bulk-parallel IoU map + cheap resolve per 64-chunk
  int nchunks = (M + 63) >> 6;
  for (int ck = 0; ck < nchunks; ++ck) {
    int start = ck << 6;
    __syncthreads();   // A: prev cross-pass done before hmask overwrite; decode done

    // step 1 (all threads): hit masks of every remaining candidate vs chunk boxes.
    // Unconditional inner loop -> broadcast ds_read_b128, fully pipelined.
    for (int j = start + tid; j < M; j += 256) {
      float4 bj = sbox[j];
      float ja = sarea[j];
      u64 hm = 0;
#pragma unroll 4
      for (int i = 0; i < 64; ++i) {
        float4 bi = sbox[start + i];   // garbage beyond M: provably masked below
        float v = iou_f(bi.x, bi.y, bi.z, bi.w, sarea[start + i],
                        bj.x, bj.y, bj.z, bj.w, ja);
        if (v > IOU_T) hm |= (1ull << i);
      }
      hmask[j] = hm;
    }
    __syncthreads();   // B: hmask ready

    // step 2 (wave 0): serial ballot resolve on precomputed bits
    if (tid < 64) {
      int l = tid, j = start + l;
      bool alive = (j < M) && (skeep[j] != 0);
      u64 mask = alive ? (hmask[j] & ((1ull << l) - 1ull)) : 0ull;
      u64 rem = ~__ballot(alive);
      for (int i = 0; i < 63; ++i) {
        if (!((rem >> i) & 1)) rem |= __ballot((mask >> i) & 1);
        else                   (void)__ballot(0);
      }
      bool kept = alive && !((rem >> l) & 1);
      skeep[j] = kept ? 1 : 0;
      u64 km = __ballot(kept);
      if (tid == 0) chunk_kept = km;
    }
    __syncthreads();   // C: chunk_kept + chunk skeep final

    // step 3 (all threads): cross-chunk suppression = one LDS read + AND
    u64 km = chunk_kept;
    for (int j = start + 64 + tid; j < M; j += 256) {
      if (skeep[j] && (hmask[j] & km)) skeep[j] = 0;
    }
  }
  __syncthreads();

  // parallel compaction: first min(total,200) kept, in sorted order
  int w = tid >> 6, l = tid & 63;
  u64 segmask[4];
  for (int s = 0; s < 4; ++s) {
    int seg = (w << 2) + s;
    bool kept = skeep[(seg << 6) + l] != 0;
    u64 bal = __ballot(kept);
    segmask[s] = bal;
    if (l == 0) segcnt[seg] = __popcll(bal);
  }
  __syncthreads();
  if (tid < 16) {
    int acc = 0;
    for (int i = 0; i < tid; ++i) acc += segcnt[i];
    segbase[tid] = acc;
  }
  __syncthreads();
  int total = segbase[15] + segcnt[15];
  for (int s = 0; s < 4; ++s) {
    int seg = (w << 2) + s;
    int p = (seg << 6) + l;
    if (skeep[p] != 0) {
      int rank = segbase[seg] + __popcll(segmask[s] & ((1ull << l) - 1ull));
      if (rank < MAXKEEP) {
        u64 k = sorted_key[((size_t)lane << 10) + p];
        u32 sbits = (u32)(k >> 32);
        int n = (int)(0xFFFFFFFFu - (u32)(k & 0xFFFFFFFFull));
        lane_key[(size_t)lane * MAXKEEP + rank] = pack_key(sbits, c * NROI + p, n);
      }
    }
  }
  if (tid == 0) keep_count[lane] = min(total, MAXKEEP);
}

// --- kernel 4: per-batch parallel top-200 (radix-select + bitonic), exact order ---
__global__ __launch_bounds__(256) void merge_kernel(
    const float* __restrict__ roi, const float* __restrict__ deltas,
    const int* __restrict__ keep_count, const u64* __restrict__ lane_key,
    float* __restrict__ out_b, float* __restrict__ out_c, float* __restrict__ out_s) {
  int b = blockIdx.x;
  int tid = threadIdx.x;

  __shared__ int hist[HSIZE];
  __shared__ int csum[256];
  __shared__ int cnts[NCLS];
  __shared__ int tb_sh, scnt_sh;
  __shared__ u64 surv[SCAP];

  for (int i = tid; i < HSIZE; i += 256) hist[i] = 0;
  for (int i = tid; i < NCLS; i += 256) cnts[i] = keep_count[b * NCLS + i];
  if (tid == 0) { tb_sh = 0; scnt_sh = 0; }
  __syncthreads();

  // histogram on top-13 mantissa bits (scores in (0.5,1): exponent constant,
  // so bucket order == score order)
  for (int s = tid; s < NCLS * MAXKEEP; s += 256) {
    int c = s / MAXKEEP, h = s % MAXKEEP;
    if (h < cnts[c]) {
      u64 k = lane_key[((size_t)(b * NCLS + c)) * MAXKEEP + h];
      u32 sb = (u32)(k >> 32);
      atomicAdd(&hist[(sb >> 10) & (HSIZE - 1)], 1);
    }
  }
  __syncthreads();

  // suffix sums; find tb = max bucket with sufsum >= 200 (0 if total < 200)
  int base = tid * 32;
  int psum = 0;
  for (int i = 0; i < 32; ++i) psum += hist[base + i];
  csum[tid] = psum;
  __syncthreads();
  if (tid == 0) {
    int acc = 0;
    for (int t = 255; t >= 0; --t) { acc += csum[t]; csum[t] = acc; }
  }
  __syncthreads();
  int acc = (tid < 255) ? csum[tid + 1] : 0;
  int local_tb = -1;
  for (int i = 31; i >= 0; --i) {
    acc += hist[base + i];
    if (acc >= MAXKEEP && local_tb < 0) local_tb = base + i;
  }
  if (local_tb >= 0) atomicMax(&tb_sh, local_tb);
  __syncthreads();
  int tb = tb_sh;

  // gather survivors (all keys in buckets >= tb; superset of exact top-200)
  for (int s = tid; s < NCLS * MAXKEEP; s += 256) {
    int c = s / MAXKEEP, h = s % MAXKEEP;
    if (h < cnts[c]) {
      u64 k = lane_key[((size_t)(b * NCLS + c)) * MAXKEEP + h];
      u32 sb = (u32)(k >> 32);
      if ((int)((sb >> 10) & (HSIZE - 1)) >= tb) {
        int pos = atomicAdd(&scnt_sh, 1);
        if (pos < SCAP) surv[pos] = k;
      }
    }
  }
  __syncthreads();
  int scnt = min(scnt_sh, SCAP);
  int size = 2;
  while (size < scnt) size <<= 1;
  for (int i = scnt + tid; i < size; i += 256) surv[i] = 0ull;
  __syncthreads();

  // bitonic sort descending by full key (score desc, flat asc)
  for (int k2 = 2; k2 <= size; k2 <<= 1) {
    for (int j = k2 >> 1; j > 0; j >>= 1) {
      for (int i = tid; i < size; i += 256) {
        int ixj = i ^ j;
        if (ixj > i) {
          u64 a = surv[i], bb = surv[ixj];
          bool swp = ((i & k2) == 0) ? (a < bb) : (a > bb);
          if (swp) { surv[i] = bb; surv[ixj] = a; }
        }
      }
      __syncthreads();
    }
  }

  // decode + write top-200 in parallel; zero-fill the rest
  for (int t = tid; t < MAXKEEP; t += 256) {
    size_t ob = ((size_t)b * MAXKEEP + t) * 4;
    if (t < scnt) {
      u64 k = surv[t];
      int flat = 131071 - (int)((k >> 15) & 0x1FFFF);
      int c = flat / NROI;
      int n = (int)((k >> 5) & 0x3FF);
      int row = b * NROI + n;
      float by1, bx1, by2, bx2;
      decode_box(roi + (size_t)row * 4, deltas + ((size_t)row * NCLS + c) * 4,
                 by1, bx1, by2, bx2);
      out_b[ob + 0] = fminf(fmaxf(by1, 0.0f), 1.0f);
      out_b[ob + 1] = fminf(fmaxf(bx1, 0.0f), 1.0f);
      out_b[ob + 2] = fminf(fmaxf(by2, 0.0f), 1.0f);
      out_b[ob + 3] = fminf(fmaxf(bx2, 0.0f), 1.0f);
      out_c[b * MAXKEEP + t] = (float)c;
      out_s[b * MAXKEEP + t] = __uint_as_float((u32)(k >> 32));
    } else {
      out_b[ob + 0] = 0.0f; out_b[ob + 1] = 0.0f;
      out_b[ob + 2] = 0.0f; out_b[ob + 3] = 0.0f;
      out_c[b * MAXKEEP + t] = 0.0f;
      out_s[b * MAXKEEP + t] = 0.0f;
    }
  }
}

extern "C" void kernel_launch(void* const* d_in, const int* in_sizes, int n_in,
                              void* d_out, int out_size, void* d_ws, size_t ws_size,
                              hipStream_t stream) {
  const float* roi    = (const float*)d_in[0];  // [8,1000,4]
  const float* deltas = (const float*)d_in[1];  // [8,1000,324]
  const float* probs  = (const float*)d_in[2];  // [8,1000,81]

  char* ws = (char*)d_ws;
  int* bg         = (int*)(ws);                   // 32000 B
  int* cand_count = (int*)(ws + 32768);           // 2592 B
  int* keep_count = (int*)(ws + 36864);           // 2592 B
  u64* lane_key   = (u64*)(ws + 40960);           // 648*200*8 = 1,036,800 B
  u64* sorted_key = (u64*)(ws + 40960 + 1081344); // 648*1024*8 = 5,308,416 B

  float* out_b = (float*)d_out;                 // [8,200,4]
  float* out_c = out_b + NB * MAXKEEP * 4;      // [8,200]
  float* out_s = out_c + NB * MAXKEEP;          // [8,200]

  bg_kernel<<<(NB * NROI + 3) / 4, 256, 0, stream>>>(probs, bg);
  gather_sort_kernel<<<NLANE, 256, 0, stream>>>(probs, bg, cand_count, sorted_key);
  nms_kernel<<<NLANE, 256, 0, stream>>>(roi, deltas, cand_count, sorted_key,
                                        keep_count, lane_key);
  merge_kernel<<<NB, 256, 0, stream>>>(roi, deltas, keep_count, lane_key,
                                       out_b, out_c, out_s);
}